// Round 5
// baseline (119.543 us; speedup 1.0000x reference)
//
#include <hip/hip_runtime.h>
#include <math.h>

// ROUND-5 PROBE: fourier_main is launched TWICE (idempotent: no atomics,
// deterministic stores only, reads nothing it globally writes; both launches
// precede fix_waves so its atomicAdd corrections are not overwritten).
// dur_us delta vs R4 (95.0us) == one fourier_main duration. This resolves the
// 4-round ambiguity between "main ~38us hiding under the fill cutoff" and
// "main ~9us, budget is harness fill/slop". Output is bit-identical to R4.

namespace {
constexpr int kNpts = 32 * 32 * 32;   // 32768 frequency points
constexpr int kHalf = kNpts / 2;      // 16384 conj-unique points (p, 32767-p conjugate)
constexpr int kNF = 1024;             // faces
constexpr int kWaves = 16;            // waves per fourier block (1024 threads)
constexpr int kFaceHalves = 2;        // face-dim split across blocks
constexpr int kFPG = kNF / (kWaves * kFaceHalves);  // 32 faces per wave
constexpr int kBlocks = (kHalf / 64) * kFaceHalves; // 512 blocks
constexpr int kNumWaves = kBlocks * kWaves;         // 8192 waves
// d_ws layout (offsets in 32-bit words):
//   [0..2)       f32 area partials (face-half 0, 1)
//   [256..)      partial grids: kFaceHalves * kHalf float2 (65536 words)
//   [65792..)    per-wave slow-pair counts: kNumWaves u32 (32 KB)
//   [73984..)    per-wave slow-pair segments: kNumWaves * segStride u32
constexpr int kGridOffW = 256;
constexpr int kCntOffW = kGridOffW + kFaceHalves * kHalf * 2;  // 65792
constexpr int kSegOffW = kCntOffW + kNumWaves;                 // 73984
constexpr int kSegStrideMax = 2048;   // = kFPG*64: a wave can never overflow
}

__device__ __forceinline__ float fract32(float x) {
#if __has_builtin(__builtin_amdgcn_fractf)
    return __builtin_amdgcn_fractf(x);
#else
    return x - floorf(x);
#endif
}

// exact f64 replica of the reference's pair case value
__device__ __forceinline__ void pair_case_f64(double x1, double x2, double x3,
                                              double& vr, double& vi) {
    const double m = (x1 + x2) * 0.5;
    const double d = m - x3;
    double sm, cm, s3, c3;
    sincos(m, &sm, &cm);
    sincos(x3, &s3, &c3);
    vr = (sm + (cm - c3) / d) / d;
    vi = (cm + (s3 - sm) / d) / d;
}

// ---- Kernel 1: face prep (in-block, LDS) + main Fourier sum, PURE f32.
// Product gate: min |product of two phase-diffs| in rev^2 <= 2.533e-5
// (= 1e-3 rad^2) -> slow. Slow pairs contribute 0 here and are recorded in
// deterministic per-wave segments (ballot compaction, no atomics). ----
__global__ __launch_bounds__(kWaves * 64, 4) void fourier_main(
        const float* __restrict__ verts, const float* __restrict__ box,
        const int* __restrict__ faces, unsigned* __restrict__ wsu,
        const float* __restrict__ xi0, const float* __restrict__ xi1,
        const float* __restrict__ xi2, int segStride) {
    const float INV_TWO_PI_F = 0.15915494f;
    const float TAUP_REV2 = 2.5330296e-5f;  // 1e-3 rad^2 in rev^2

    __shared__ float4 rec[512][3];        // 24 KB: per-face {a,b,c coords, w}
    __shared__ float accR[kWaves][64];    // 4 KB
    __shared__ float accI[kWaves][64];    // 4 KB
    __shared__ float wsum[8];

    const int t = threadIdx.x;
    const int l = t & 63;                 // lane -> point within group
    const int w = t >> 6;                 // wave -> face subgroup
    const int pb = blockIdx.x & 255;      // point group
    const int fh = blockIdx.x >> 8;       // face half

    // ---- in-block face prep: threads 0..511 each build one face record ----
    if (t < 512) {
        const int f = fh * 512 + t;
        const float lo0 = box[0], lo1 = box[2], lo2 = box[4];
        const int ia = faces[3 * f + 0], ib = faces[3 * f + 1], ic = faces[3 * f + 2];
        const float ax = verts[3 * ia + 0] - lo0, ay = verts[3 * ia + 1] - lo1, az = verts[3 * ia + 2] - lo2;
        const float bx = verts[3 * ib + 0] - lo0, by = verts[3 * ib + 1] - lo1, bz = verts[3 * ib + 2] - lo2;
        const float cx = verts[3 * ic + 0] - lo0, cy = verts[3 * ic + 1] - lo1, cz = verts[3 * ic + 2] - lo2;
        const float e1x = bx - ax, e1y = by - ay, e1z = bz - az;
        const float e2x = cx - ax, e2y = cy - ay, e2z = cz - az;
        const float crx = e1y * e2z - e1z * e2y;
        const float cry = e1z * e2x - e1x * e2z;
        const float crz = e1x * e2y - e1y * e2x;
        const float area = 0.5f * sqrtf(crx * crx + cry * cry + crz * crz);
        rec[t][0] = make_float4(ax, ay, az, bx);
        rec[t][1] = make_float4(by, bz, cx, cy);
        rec[t][2] = make_float4(cz, area * 0.025330296f, 0.0f, 0.0f);
        // wave-reduce area over waves 0..7
        float a = area;
        a += __shfl_down(a, 32, 64);
        a += __shfl_down(a, 16, 64);
        a += __shfl_down(a, 8, 64);
        a += __shfl_down(a, 4, 64);
        a += __shfl_down(a, 2, 64);
        a += __shfl_down(a, 1, 64);
        if (l == 0) wsum[w] = a;
    }
    __syncthreads();
    if (t == 0 && pb == 0) {   // one block per half publishes its area partial
        float s = wsum[0];
#pragma unroll
        for (int j = 1; j < 8; ++j) s += wsum[j];
        ((float*)wsu)[fh] = s;
    }

    // ---- main loop ----
    const int p = pb * 64 + l;            // p in [0, kHalf)
    const int i2 = p & 31, i1 = (p >> 5) & 31, i0 = p >> 10;
    const float xxr = xi0[i0] * INV_TWO_PI_F;
    const float xyr = xi1[i1] * INV_TWO_PI_F;
    const float xzr = xi2[i2] * INV_TWO_PI_F;

    float re = 0.0f, im = 0.0f;
    unsigned cntLocal = 0;
    const int waveId = blockIdx.x * kWaves + w;
    unsigned* seg = wsu + kSegOffW + (size_t)waveId * segStride;
    const int fbase = fh * 512 + w * kFPG;
    const int rbase = w * kFPG;

#pragma unroll 4
    for (int i = 0; i < kFPG; ++i) {
        const float4 q0 = rec[rbase + i][0];
        const float4 q1 = rec[rbase + i][1];
        const float4 q2 = rec[rbase + i][2];
        // phases in revolutions, f32 (F has O(1) derivatives; f32 phase noise
        // -> ~1e-5-level output error; denominators gated below)
        const float ra = fmaf(xzr, q0.z, fmaf(xyr, q0.y, xxr * q0.x));
        const float rb = fmaf(xzr, q1.y, fmaf(xyr, q1.x, xxr * q0.w));
        const float rc = fmaf(xzr, q2.x, fmaf(xyr, q1.w, xxr * q1.z));
        const float fdab = rb - ra, fdbc = rc - rb, fdca = ra - rc;
        const float d1 = fdab * fdca;   // rev^2 pair products (R1 gate)
        const float d2 = fdbc * fdab;
        const float d3 = fdca * fdbc;
        // compiles to v_min3 with |.| input modifiers
        const float mn = fminf(fminf(fabsf(d1), fabsf(d2)), fabsf(d3));
        const bool slow = !(mn > TAUP_REV2);
        if (!slow) {
            // fast path: v_fract -> hw v_sin/v_cos (rev input), 1 rcp;
            // area/(4pi^2) folded into the reciprocal
            const float R3w = __builtin_amdgcn_rcpf(d1 * fdbc) * q2.y;
            const float r1 = fdbc * R3w, r2 = fdca * R3w, r3 = fdab * R3w;
            const float fa = fract32(ra);
            const float fb = fract32(rb);
            const float fc = fract32(rc);
            const float sa = __builtin_amdgcn_sinf(fa), ca = __builtin_amdgcn_cosf(fa);
            const float sb = __builtin_amdgcn_sinf(fb), cb = __builtin_amdgcn_cosf(fb);
            const float sc = __builtin_amdgcn_sinf(fc), cc = __builtin_amdgcn_cosf(fc);
            re = fmaf(cc, r3, fmaf(cb, r2, fmaf(ca, r1, re)));
            im = fmaf(-sc, r3, fmaf(-sb, r2, fmaf(-sa, r1, im)));
        }
        // deterministic compaction of slow pairs into this wave's segment
        const unsigned long long m = __ballot(slow);
        if (m) {
            if (slow) {
                const unsigned pos =
                    cntLocal + (unsigned)__popcll(m & ((1ull << l) - 1ull));
                if ((int)pos < segStride)
                    seg[pos] = ((unsigned)(fbase + i) << 14) | (unsigned)p;
            }
            cntLocal += (unsigned)__popcll(m);
        }
    }
    if (l == 0) wsu[kCntOffW + waveId] = cntLocal;  // always write (ws is poisoned)

    // reduce kWaves partials per point; write this face-half's partial grid
    accR[w][l] = re;
    accI[w][l] = im;
    __syncthreads();
    if (w == 0) {
        float R = accR[0][l], I = accI[0][l];
#pragma unroll
        for (int g = 1; g < kWaves; ++g) { R += accR[g][l]; I += accI[g][l]; }
        float2* pg = (float2*)(wsu + kGridOffW);
        pg[(size_t)fh * kHalf + p] = make_float2(R, I);
    }
}

// ---- Kernel 2: thread-per-wave slow-pair replay. 8192 threads; each walks
// ONLY its own wave's segment (almost always empty under the product gate),
// replays the exact f64 reference region logic, atomic-adds into the half-0
// partial grid. ----
__global__ __launch_bounds__(256) void fix_waves(
        const float* __restrict__ verts, const float* __restrict__ box,
        const int* __restrict__ faces, const float* __restrict__ xi0,
        const float* __restrict__ xi1, const float* __restrict__ xi2,
        unsigned* __restrict__ wsu, int segStride) {
    const double SEPS = __builtin_sqrt(1.19209e-07);  // matches float(np.sqrt(EPS))
    const double TWO_PI = 6.283185307179586;
    const double INV_TWO_PI = 0.15915494309189535;

    const int s = blockIdx.x * 256 + threadIdx.x;   // wave id
    if (s >= kNumWaves) return;
    unsigned n = wsu[kCntOffW + s];
    if (n == 0) return;
    if (n > (unsigned)segStride) n = (unsigned)segStride;
    const unsigned* seg = wsu + kSegOffW + (size_t)s * segStride;
    float* pg = (float*)(wsu + kGridOffW);

    for (unsigned j = 0; j < n; ++j) {
        const unsigned e = seg[j];
        const int p = (int)(e & 16383u);
        const int f = (int)(e >> 14);
        const int i2 = p & 31, i1 = (p >> 5) & 31, i0 = p >> 10;
        const double xxd = (double)xi0[i0] * INV_TWO_PI;
        const double xyd = (double)xi1[i1] * INV_TWO_PI;
        const double xzd = (double)xi2[i2] * INV_TWO_PI;
        const double lo0 = (double)box[0], lo1 = (double)box[2], lo2 = (double)box[4];
        const int ia = faces[3 * f + 0], ib = faces[3 * f + 1], ic = faces[3 * f + 2];
        const double ax = (double)verts[3 * ia + 0] - lo0, ay = (double)verts[3 * ia + 1] - lo1, az = (double)verts[3 * ia + 2] - lo2;
        const double bx = (double)verts[3 * ib + 0] - lo0, by = (double)verts[3 * ib + 1] - lo1, bz = (double)verts[3 * ib + 2] - lo2;
        const double cx = (double)verts[3 * ic + 0] - lo0, cy = (double)verts[3 * ic + 1] - lo1, cz = (double)verts[3 * ic + 2] - lo2;
        // f32 area exactly as the fast-path prep computes it
        const float axf = (float)ax, ayf = (float)ay, azf = (float)az;
        const float bxf = (float)bx, byf = (float)by, bzf = (float)bz;
        const float cxf = (float)cx, cyf = (float)cy, czf = (float)cz;
        const float e1x = bxf - axf, e1y = byf - ayf, e1z = bzf - azf;
        const float e2x = cxf - axf, e2y = cyf - ayf, e2z = czf - azf;
        const float crx = e1y * e2z - e1z * e2y;
        const float cry = e1z * e2x - e1x * e2z;
        const float crz = e1x * e2y - e1y * e2x;
        const float areaf = 0.5f * sqrtf(crx * crx + cry * cry + crz * crz);
        const double rad = fma(xzd, az, fma(xyd, ay, xxd * ax));
        const double rbd = fma(xzd, bz, fma(xyd, by, xxd * bx));
        const double rcd = fma(xzd, cz, fma(xyd, cy, xxd * cx));
        const double xa = rad * TWO_PI, xb = rbd * TWO_PI, xc = rcd * TWO_PI;
        const double dAB = xb - xa, dBC = xc - xb, dCA = xa - xc;
        const double aab = fabs(dAB), abc = fabs(dBC), aca = fabs(dCA);
        const bool s2 = aab < SEPS, s3 = abc < SEPS, s4 = aca < SEPS;
        const bool c2 = aab <= SEPS, c3 = abc <= SEPS, c4 = aca <= SEPS;
        const bool R1 = (s2 && s3) || (s3 && s4) || (s4 && s2);
        const bool R2 = c2 && !R1;
        const bool R3b = c3 && !R2 && !R1;
        const bool R4 = c4 && !R3b && !R2 && !R1;
        double vr, vi;
        if (R1) {
            const double m = ((xa + xb) + xc) / 3.0;
            double sm, cm;
            sincos(m, &sm, &cm);
            vr = cm / 2.0;
            vi = -sm / 2.0;
        } else if (R2) {
            pair_case_f64(xa, xb, xc, vr, vi);
        } else if (R3b) {
            pair_case_f64(xb, xc, xa, vr, vi);
        } else if (R4) {
            pair_case_f64(xc, xa, xb, vr, vi);
        } else {
            double sa, ca, sb, cb, sc, cc;
            sincos(xa, &sa, &ca);
            sincos(xb, &sb, &cb);
            sincos(xc, &sc, &cc);
            const double da = dAB * dCA, db = dBC * dAB, dc = dCA * dBC;
            vr = (ca / da + cb / db) + cc / dc;
            vi = -((sa / da + sb / db) + sc / dc);
        }
        atomicAdd(&pg[2 * p + 0], areaf * (float)vr);
        atomicAdd(&pg[2 * p + 1], areaf * (float)vi);
    }
}

// ---- Kernel 3: combine face-half partials, scale by 2/meshar, mirror-write ----
__global__ __launch_bounds__(256) void combine(
        const unsigned* __restrict__ wsu, float* __restrict__ out, int interleaved) {
    const int p = blockIdx.x * 256 + threadIdx.x;  // [0, kHalf)
    const float* wsf = (const float*)wsu;
    const float meshar = wsf[0] + wsf[1];
    const float inv2 = 2.0f / meshar;
    const float2* pg = (const float2*)(wsu + kGridOffW);
    const float2 a = pg[p];
    const float2 b = pg[kHalf + p];
    const float R = (a.x + b.x) * inv2;
    const float I = (a.y + b.y) * inv2;
    const int q = kNpts - 1 - p;
    if (interleaved) {
        ((float2*)out)[p] = make_float2(R, I);
        ((float2*)out)[q] = make_float2(R, -I);
    } else {
        out[p] = R;
        out[q] = R;
    }
}

extern "C" void kernel_launch(void* const* d_in, const int* in_sizes, int n_in,
                              void* d_out, int out_size, void* d_ws, size_t ws_size,
                              hipStream_t stream) {
    const float* verts = (const float*)d_in[0];
    const float* box   = (const float*)d_in[1];
    const float* xi0v  = (const float*)d_in[2];
    const float* xi1v  = (const float*)d_in[3];
    const float* xi2v  = (const float*)d_in[4];
    const int*   faces = (const int*)d_in[5];
    unsigned* wsu = (unsigned*)d_ws;

    const int interleaved = (out_size == 2 * kNpts) ? 1 : 0;

    // segment stride: worst case (2048) fits in 256 MiB ws; degrade if smaller
    int segStride = kSegStrideMax;
    const size_t wsWords = ws_size / 4;
    if (wsWords < (size_t)kSegOffW + (size_t)kNumWaves * segStride) {
        segStride = (wsWords > (size_t)kSegOffW)
                        ? (int)((wsWords - kSegOffW) / kNumWaves)
                        : 0;
    }

    // PROBE: fourier_main launched twice (idempotent; both BEFORE fix_waves so
    // atomic corrections are not overwritten). dur delta == main's duration.
    hipLaunchKernelGGL(fourier_main, dim3(kBlocks), dim3(kWaves * 64), 0, stream,
                       verts, box, faces, wsu, xi0v, xi1v, xi2v, segStride);
    hipLaunchKernelGGL(fourier_main, dim3(kBlocks), dim3(kWaves * 64), 0, stream,
                       verts, box, faces, wsu, xi0v, xi1v, xi2v, segStride);
    hipLaunchKernelGGL(fix_waves, dim3(kNumWaves / 256), dim3(256), 0, stream,
                       verts, box, faces, xi0v, xi1v, xi2v, wsu, segStride);
    hipLaunchKernelGGL(combine, dim3(kHalf / 256), dim3(256), 0, stream,
                       wsu, (float*)d_out, interleaved);
}

// Round 6
// 90.596 us; speedup vs baseline: 1.3195x; 1.3195x over previous
//
#include <hip/hip_runtime.h>
#include <math.h>

// Fully-fused single-kernel version. Each block owns ONE 64-point group and
// ALL 1024 faces (prep'd into LDS). Consequences:
//  - no cross-block dependencies at all: meshar is computed in-block, slow
//    (near-degenerate) pairs detected by a block concern only its own points,
//    corrections fold into the block's LDS accumulators, block writes final
//    mirrored output. 4 dispatches -> 1 (kills fix_waves' serialized segment
//    walk and 3 launch gaps: the ~31us residual identified by the R5 probe).
//  - ws is entirely unused (fill remains, harness-side).

namespace {
constexpr int kNpts = 32 * 32 * 32;   // 32768 frequency points
constexpr int kHalf = kNpts / 2;      // 16384 conj-unique points
constexpr int kNF = 1024;             // faces
constexpr int kThreads = 1024;        // 16 waves
constexpr int kWaves = 16;
constexpr int kFPW = kNF / kWaves;    // 64 faces per wave
constexpr int kBlocks = kHalf / 64;   // 256 blocks = one per 64-point group
constexpr int kSlowCap = 1536;        // LDS slow-pair list (6 KB); overflow
                                      // handled exactly via inline cold path
}

__device__ __forceinline__ float fract32(float x) {
#if __has_builtin(__builtin_amdgcn_fractf)
    return __builtin_amdgcn_fractf(x);
#else
    return x - floorf(x);
#endif
}

// exact f64 replica of the reference's pair case value
__device__ __forceinline__ void pair_case_f64(double x1, double x2, double x3,
                                              double& vr, double& vi) {
    const double m = (x1 + x2) * 0.5;
    const double d = m - x3;
    double sm, cm, s3, c3;
    sincos(m, &sm, &cm);
    sincos(x3, &s3, &c3);
    vr = (sm + (cm - c3) / d) / d;
    vi = (cm + (s3 - sm) / d) / d;
}

// Exact f64 replica of the reference region logic for one (face, point) pair.
// Returns the area-weighted (pre-meshar-scale) contribution. __noinline__
// keeps the f64/ocml-sincos code out of the hot loop's register allocation.
__device__ __noinline__ void slow_exact(
        int f, int p, const float* __restrict__ verts,
        const float* __restrict__ box, const int* __restrict__ faces,
        const float* __restrict__ xi0, const float* __restrict__ xi1,
        const float* __restrict__ xi2, float& cr, float& ci) {
    const double SEPS = __builtin_sqrt(1.19209e-07);  // matches float(np.sqrt(EPS))
    const double TWO_PI = 6.283185307179586;
    const double INV_TWO_PI = 0.15915494309189535;

    const int i2 = p & 31, i1 = (p >> 5) & 31, i0 = p >> 10;
    const double xxd = (double)xi0[i0] * INV_TWO_PI;
    const double xyd = (double)xi1[i1] * INV_TWO_PI;
    const double xzd = (double)xi2[i2] * INV_TWO_PI;
    const double lo0 = (double)box[0], lo1 = (double)box[2], lo2 = (double)box[4];
    const int ia = faces[3 * f + 0], ib = faces[3 * f + 1], ic = faces[3 * f + 2];
    const double ax = (double)verts[3 * ia + 0] - lo0, ay = (double)verts[3 * ia + 1] - lo1, az = (double)verts[3 * ia + 2] - lo2;
    const double bx = (double)verts[3 * ib + 0] - lo0, by = (double)verts[3 * ib + 1] - lo1, bz = (double)verts[3 * ib + 2] - lo2;
    const double cx = (double)verts[3 * ic + 0] - lo0, cy = (double)verts[3 * ic + 1] - lo1, cz = (double)verts[3 * ic + 2] - lo2;
    // f32 area exactly as the fast-path prep computes it
    const float axf = (float)ax, ayf = (float)ay, azf = (float)az;
    const float bxf = (float)bx, byf = (float)by, bzf = (float)bz;
    const float cxf = (float)cx, cyf = (float)cy, czf = (float)cz;
    const float e1x = bxf - axf, e1y = byf - ayf, e1z = bzf - azf;
    const float e2x = cxf - axf, e2y = cyf - ayf, e2z = czf - azf;
    const float crx = e1y * e2z - e1z * e2y;
    const float cry = e1z * e2x - e1x * e2z;
    const float crz = e1x * e2y - e1y * e2x;
    const float areaf = 0.5f * sqrtf(crx * crx + cry * cry + crz * crz);
    const double rad = fma(xzd, az, fma(xyd, ay, xxd * ax));
    const double rbd = fma(xzd, bz, fma(xyd, by, xxd * bx));
    const double rcd = fma(xzd, cz, fma(xyd, cy, xxd * cx));
    const double xa = rad * TWO_PI, xb = rbd * TWO_PI, xc = rcd * TWO_PI;
    const double dAB = xb - xa, dBC = xc - xb, dCA = xa - xc;
    const double aab = fabs(dAB), abc = fabs(dBC), aca = fabs(dCA);
    const bool s2 = aab < SEPS, s3 = abc < SEPS, s4 = aca < SEPS;
    const bool c2 = aab <= SEPS, c3 = abc <= SEPS, c4 = aca <= SEPS;
    const bool R1 = (s2 && s3) || (s3 && s4) || (s4 && s2);
    const bool R2 = c2 && !R1;
    const bool R3b = c3 && !R2 && !R1;
    const bool R4 = c4 && !R3b && !R2 && !R1;
    double vr, vi;
    if (R1) {
        const double m = ((xa + xb) + xc) / 3.0;
        double sm, cm;
        sincos(m, &sm, &cm);
        vr = cm / 2.0;
        vi = -sm / 2.0;
    } else if (R2) {
        pair_case_f64(xa, xb, xc, vr, vi);
    } else if (R3b) {
        pair_case_f64(xb, xc, xa, vr, vi);
    } else if (R4) {
        pair_case_f64(xc, xa, xb, vr, vi);
    } else {
        double sa, ca, sb, cb, sc, cc;
        sincos(xa, &sa, &ca);
        sincos(xb, &sb, &cb);
        sincos(xc, &sc, &cc);
        const double da = dAB * dCA, db = dBC * dAB, dc = dCA * dBC;
        vr = (ca / da + cb / db) + cc / dc;
        vi = -((sa / da + sb / db) + sc / dc);
    }
    cr = areaf * (float)vr;
    ci = areaf * (float)vi;
}

__global__ __launch_bounds__(kThreads, 4) void fourier_all(
        const float* __restrict__ verts, const float* __restrict__ box,
        const int* __restrict__ faces, const float* __restrict__ xi0,
        const float* __restrict__ xi1, const float* __restrict__ xi2,
        float* __restrict__ out, int interleaved) {
    const float INV_TWO_PI_F = 0.15915494f;
    const float TAUP_REV2 = 2.5330296e-5f;  // 1e-3 rad^2 in rev^2 (product gate)

    __shared__ float4 rec[kNF][3];        // 48 KB: per-face {a,b,c coords, w}
    __shared__ float accR[kWaves][64];    // 4 KB
    __shared__ float accI[kWaves][64];    // 4 KB
    __shared__ unsigned slowList[kSlowCap];  // 6 KB
    __shared__ unsigned slowCnt;
    __shared__ float wsum[kWaves];
    __shared__ float meshar_sh;

    const int t = threadIdx.x;
    const int l = t & 63;                 // lane -> point within group
    const int w = t >> 6;                 // wave -> face subgroup
    const int pb = blockIdx.x;            // point group [0,256)

    if (t == 0) slowCnt = 0;

    // ---- in-block face prep: thread t builds face t (all 1024 faces) ----
    {
        const int f = t;
        const float lo0 = box[0], lo1 = box[2], lo2 = box[4];
        const int ia = faces[3 * f + 0], ib = faces[3 * f + 1], ic = faces[3 * f + 2];
        const float ax = verts[3 * ia + 0] - lo0, ay = verts[3 * ia + 1] - lo1, az = verts[3 * ia + 2] - lo2;
        const float bx = verts[3 * ib + 0] - lo0, by = verts[3 * ib + 1] - lo1, bz = verts[3 * ib + 2] - lo2;
        const float cx = verts[3 * ic + 0] - lo0, cy = verts[3 * ic + 1] - lo1, cz = verts[3 * ic + 2] - lo2;
        const float e1x = bx - ax, e1y = by - ay, e1z = bz - az;
        const float e2x = cx - ax, e2y = cy - ay, e2z = cz - az;
        const float crx = e1y * e2z - e1z * e2y;
        const float cry = e1z * e2x - e1x * e2z;
        const float crz = e1x * e2y - e1y * e2x;
        const float area = 0.5f * sqrtf(crx * crx + cry * cry + crz * crz);
        rec[f][0] = make_float4(ax, ay, az, bx);
        rec[f][1] = make_float4(by, bz, cx, cy);
        rec[f][2] = make_float4(cz, area * 0.025330296f, 0.0f, 0.0f);
        // wave-reduce area; 16 wave partials -> meshar
        float a = area;
        a += __shfl_down(a, 32, 64);
        a += __shfl_down(a, 16, 64);
        a += __shfl_down(a, 8, 64);
        a += __shfl_down(a, 4, 64);
        a += __shfl_down(a, 2, 64);
        a += __shfl_down(a, 1, 64);
        if (l == 0) wsum[w] = a;
    }
    __syncthreads();
    if (t == 0) {
        float s = wsum[0];
#pragma unroll
        for (int j = 1; j < kWaves; ++j) s += wsum[j];
        meshar_sh = s;
    }

    // ---- main loop: wave w sums faces [w*64, w*64+64) for point p ----
    const int p = pb * 64 + l;            // p in [0, kHalf)
    const int i2 = p & 31, i1 = (p >> 5) & 31, i0 = p >> 10;
    const float xxr = xi0[i0] * INV_TWO_PI_F;
    const float xyr = xi1[i1] * INV_TWO_PI_F;
    const float xzr = xi2[i2] * INV_TWO_PI_F;

    float re = 0.0f, im = 0.0f;
    const int fbase = w * kFPW;

#pragma unroll 4
    for (int i = 0; i < kFPW; ++i) {
        const float4 q0 = rec[fbase + i][0];
        const float4 q1 = rec[fbase + i][1];
        const float4 q2 = rec[fbase + i][2];
        // phases in revolutions, f32 (F has O(1) derivatives; f32 phase noise
        // -> ~1e-5-level output error; denominators gated below)
        const float ra = fmaf(xzr, q0.z, fmaf(xyr, q0.y, xxr * q0.x));
        const float rb = fmaf(xzr, q1.y, fmaf(xyr, q1.x, xxr * q0.w));
        const float rc = fmaf(xzr, q2.x, fmaf(xyr, q1.w, xxr * q1.z));
        const float fdab = rb - ra, fdbc = rc - rb, fdca = ra - rc;
        const float d1 = fdab * fdca;   // rev^2 pair products (product gate)
        const float d2 = fdbc * fdab;
        const float d3 = fdca * fdbc;
        const float mn = fminf(fminf(fabsf(d1), fabsf(d2)), fabsf(d3));
        if (mn > TAUP_REV2) {
            // fast path: v_fract -> hw v_sin/v_cos (rev input), 1 rcp;
            // area/(4pi^2) folded into the reciprocal
            const float R3w = __builtin_amdgcn_rcpf(d1 * fdbc) * q2.y;
            const float r1 = fdbc * R3w, r2 = fdca * R3w, r3 = fdab * R3w;
            const float fa = fract32(ra);
            const float fb = fract32(rb);
            const float fc = fract32(rc);
            const float sa = __builtin_amdgcn_sinf(fa), ca = __builtin_amdgcn_cosf(fa);
            const float sb = __builtin_amdgcn_sinf(fb), cb = __builtin_amdgcn_cosf(fb);
            const float sc = __builtin_amdgcn_sinf(fc), cc = __builtin_amdgcn_cosf(fc);
            re = fmaf(cc, r3, fmaf(cb, r2, fmaf(ca, r1, re)));
            im = fmaf(-sc, r3, fmaf(-sb, r2, fmaf(-sa, r1, im)));
        } else {
            // rare: defer to block-local LDS list; exact inline on overflow
            const unsigned pos = atomicAdd(&slowCnt, 1u);
            if (pos < (unsigned)kSlowCap) {
                slowList[pos] = ((unsigned)(fbase + i) << 6) | (unsigned)l;
            } else {
                float cr, ci;
                slow_exact(fbase + i, p, verts, box, faces, xi0, xi1, xi2, cr, ci);
                re += cr;
                im += ci;
            }
        }
    }

    accR[w][l] = re;
    accI[w][l] = im;
    __syncthreads();

    // ---- block-local slow-pair replay, 1024 threads wide ----
    {
        unsigned n = slowCnt;
        if (n > (unsigned)kSlowCap) n = (unsigned)kSlowCap;
        for (unsigned j = (unsigned)t; j < n; j += (unsigned)kThreads) {
            const unsigned e = slowList[j];
            const int f = (int)(e >> 6);
            const int lane = (int)(e & 63u);
            float cr, ci;
            slow_exact(f, pb * 64 + lane, verts, box, faces, xi0, xi1, xi2, cr, ci);
            atomicAdd(&accR[0][lane], cr);
            atomicAdd(&accI[0][lane], ci);
        }
    }
    __syncthreads();

    // ---- final reduce + scale + mirror write ----
    if (t < 64) {
        float R = accR[0][l], I = accI[0][l];
#pragma unroll
        for (int g = 1; g < kWaves; ++g) { R += accR[g][l]; I += accI[g][l]; }
        const float inv2 = 2.0f / meshar_sh;
        R *= inv2;
        I *= inv2;
        const int q = kNpts - 1 - p;
        if (interleaved) {
            ((float2*)out)[p] = make_float2(R, I);
            ((float2*)out)[q] = make_float2(R, -I);
        } else {
            out[p] = R;
            out[q] = R;
        }
    }
}

extern "C" void kernel_launch(void* const* d_in, const int* in_sizes, int n_in,
                              void* d_out, int out_size, void* d_ws, size_t ws_size,
                              hipStream_t stream) {
    const float* verts = (const float*)d_in[0];
    const float* box   = (const float*)d_in[1];
    const float* xi0v  = (const float*)d_in[2];
    const float* xi1v  = (const float*)d_in[3];
    const float* xi2v  = (const float*)d_in[4];
    const int*   faces = (const int*)d_in[5];
    (void)d_ws; (void)ws_size;

    const int interleaved = (out_size == 2 * kNpts) ? 1 : 0;

    hipLaunchKernelGGL(fourier_all, dim3(kBlocks), dim3(kThreads), 0, stream,
                       verts, box, faces, xi0v, xi1v, xi2v,
                       (float*)d_out, interleaved);
}